// Round 13
// baseline (121.622 us; speedup 1.0000x reference)
//
#include <hip/hip_runtime.h>
#include <stdint.h>

typedef unsigned char u8;
typedef unsigned short u16;
typedef unsigned int u32;
typedef long long i64;
typedef __attribute__((ext_vector_type(8))) short short8;
typedef __attribute__((ext_vector_type(4))) float f32x4;
typedef __attribute__((ext_vector_type(16))) float f32x16;

#define BATCH 16
#define CCH   512
#define NPIX  1024
#define NGRP  8
#define CPG   64
#define NHEAD 4
#define HDIM  128

__device__ __forceinline__ u16 f2bf(float f) {
  union { float f; u32 u; } v; v.f = f;
  u32 u = v.u;
  u32 r = (u + 0x7FFFu + ((u >> 16) & 1u)) >> 16;
  return (u16)r;
}
__device__ __forceinline__ u8 f2fp8(float f) {
  return (u8)(__builtin_amdgcn_cvt_pk_fp8_f32(f, 0.f, 0, false) & 0xff);
}
__device__ __forceinline__ u32 pack4_fp8(float a, float b, float c, float d) {
  u32 w = (u32)__builtin_amdgcn_cvt_pk_fp8_f32(a, b, 0, false);
  w = (u32)__builtin_amdgcn_cvt_pk_fp8_f32(c, d, (int)w, true);
  return w;
}

// async global->LDS, 16B per lane; dest = wave-uniform base + lane*16
__device__ __forceinline__ void gload16(const void* g, void* l) {
  typedef __attribute__((address_space(3))) u32 L;
  typedef __attribute__((address_space(1))) const u32 G;
  __builtin_amdgcn_global_load_lds((G*)(uintptr_t)g, (L*)(u32)(uintptr_t)l, 16, 0, 0);
}

#define PLSWAP(a, b) asm("v_permlane32_swap_b32 %0, %1" : "+v"(a), "+v"(b))

// 512B-pitch swizzled LDS fragment read (rows packed 4-per-512B, 4-bit XOR) - bf16 GEMM
__device__ __forceinline__ short8 rd512(const char* base, int r, int ck, int hi) {
  int byte = ((r >> 2) * 512) +
             ((((r & 3) * 128) + ck * 32 + hi * 16) ^ (((r >> 2) & 15) << 4));
  return *reinterpret_cast<const short8*>(base + byte);
}

// softmax pack (16 scores of one 32-kv half-tile) -> 2 fp8 P-fragments; lane-local psum.
// sn[r] = S[kv_local][q], kv_local = (r&3)+8*(r>>2)+4*hi.
__device__ __forceinline__ float softmax_pack16(const f32x16& sn, float qs2, i64* pf) {
  float p0, p1, p2, p3, ps;
  u32 w0, w1, w2, w3;
  p0 = exp2f(sn[0]*qs2);  p1 = exp2f(sn[1]*qs2);
  p2 = exp2f(sn[2]*qs2);  p3 = exp2f(sn[3]*qs2);
  ps = (p0+p1)+(p2+p3);  w0 = pack4_fp8(p0, p1, p2, p3);        // kv {0..3}+4hi
  p0 = exp2f(sn[4]*qs2);  p1 = exp2f(sn[5]*qs2);
  p2 = exp2f(sn[6]*qs2);  p3 = exp2f(sn[7]*qs2);
  ps += (p0+p1)+(p2+p3); w1 = pack4_fp8(p0, p1, p2, p3);        // kv {8..11}+4hi
  p0 = exp2f(sn[8]*qs2);  p1 = exp2f(sn[9]*qs2);
  p2 = exp2f(sn[10]*qs2); p3 = exp2f(sn[11]*qs2);
  ps += (p0+p1)+(p2+p3); w2 = pack4_fp8(p0, p1, p2, p3);        // kv {16..19}+4hi
  p0 = exp2f(sn[12]*qs2); p1 = exp2f(sn[13]*qs2);
  p2 = exp2f(sn[14]*qs2); p3 = exp2f(sn[15]*qs2);
  ps += (p0+p1)+(p2+p3); w3 = pack4_fp8(p0, p1, p2, p3);        // kv {24..27}+4hi
  PLSWAP(w0, w1);   // pf0: byte j -> kv = hi*8 + j   (kv 0..15)
  PLSWAP(w2, w3);   // pf1: byte j -> kv = 16 + hi*8 + j (kv 16..31)
  pf[0] = (i64)(((unsigned long long)w1 << 32) | w0);
  pf[1] = (i64)(((unsigned long long)w3 << 32) | w2);
  return ps;
}

// ---------------- GroupNorm partial stats ----------------
__global__ void gn_stats_k(const float* __restrict__ x, float* __restrict__ part) {
  int bg = blockIdx.x >> 3, sl = blockIdx.x & 7;
  const float* p = x + (size_t)bg * (CPG * NPIX) + sl * 8192;
  float s = 0.f, ss = 0.f;
  for (int i = threadIdx.x; i < 2048; i += 256) {
    float4 v = reinterpret_cast<const float4*>(p)[i];
    s  += v.x + v.y + v.z + v.w;
    ss += v.x*v.x + v.y*v.y + v.z*v.z + v.w*v.w;
  }
  for (int o = 32; o > 0; o >>= 1) { s += __shfl_down(s, o); ss += __shfl_down(ss, o); }
  __shared__ float sh[8];
  int wid = threadIdx.x >> 6;
  if ((threadIdx.x & 63) == 0) { sh[wid*2] = s; sh[wid*2+1] = ss; }
  __syncthreads();
  if (threadIdx.x == 0) {
    part[blockIdx.x*2]   = sh[0]+sh[2]+sh[4]+sh[6];
    part[blockIdx.x*2+1] = sh[1]+sh[3]+sh[5]+sh[7];
  }
}

// ---------------- GroupNorm apply + transpose -> token-major bf16 xnT[tok][512] ----------------
__global__ __launch_bounds__(256) void gn_apply_t(const float* __restrict__ x,
                                                  const float* __restrict__ gamma,
                                                  const float* __restrict__ beta,
                                                  const float* __restrict__ part,
                                                  u16* __restrict__ xnT) {
  const int p0 = blockIdx.x * 64;
  const int c0 = blockIdx.y * 64;
  const int b  = blockIdx.z;
  __shared__ float lt[64][66];

  const int bg = b * NGRP + (c0 >> 6);
  float s = 0.f, ss = 0.f;
  #pragma unroll
  for (int k2 = 0; k2 < 8; ++k2) { s += part[(bg*8 + k2)*2]; ss += part[(bg*8 + k2)*2 + 1]; }
  const float invn = 1.f / (float)(CPG * NPIX);
  const float mean = s * invn;
  const float rstd = rsqrtf(ss * invn - mean * mean + 1e-5f);

  const int t = threadIdx.x;
  #pragma unroll
  for (int pass = 0; pass < 4; ++pass) {
    int c   = c0 + (t >> 4) + pass * 16;
    int pix = p0 + (t & 15) * 4;
    float ga = gamma[c] * rstd;
    float be = beta[c] - mean * ga;
    float4 v = *reinterpret_cast<const float4*>(&x[((size_t)(b*CCH + c)) * NPIX + pix]);
    int pl = (t & 15) * 4, cl = (t >> 4) + pass * 16;
    lt[pl+0][cl] = v.x*ga + be;
    lt[pl+1][cl] = v.y*ga + be;
    lt[pl+2][cl] = v.z*ga + be;
    lt[pl+3][cl] = v.w*ga + be;
  }
  __syncthreads();
  const int pl = t >> 2, cq = (t & 3) * 16;
  u32 wbuf[8];
  #pragma unroll
  for (int e = 0; e < 8; ++e) {
    u16 lo = f2bf(lt[pl][cq + e*2]);
    u16 hi = f2bf(lt[pl][cq + e*2 + 1]);
    wbuf[e] = (u32)lo | ((u32)hi << 16);
  }
  u32* dst = (u32*)&xnT[((size_t)(b*NPIX + p0 + pl)) * CCH + c0 + cq];
  #pragma unroll
  for (int e = 0; e < 8; ++e) dst[e] = wbuf[e];
}

// ---------------- fp32 -> bf16 weights ----------------
__global__ void f2bf_all(const float* __restrict__ wqkv, const float* __restrict__ wproj,
                         u16* __restrict__ wq, u16* __restrict__ wp) {
  int i = blockIdx.x * 256 + threadIdx.x;
  float4 v; u16* dst;
  if (i < 196608) {
    v = reinterpret_cast<const float4*>(wqkv)[i];
    dst = wq + (size_t)i * 4;
  } else {
    v = reinterpret_cast<const float4*>(wproj)[i - 196608];
    dst = wp + (size_t)(i - 196608) * 4;
  }
  u32 lo = (u32)f2bf(v.x) | ((u32)f2bf(v.y) << 16);
  u32 hi = (u32)f2bf(v.z) | ((u32)f2bf(v.w) << 16);
  *reinterpret_cast<uint2*>(dst) = make_uint2(lo, hi);
}

// ---------------- merged QKV GEMM (bf16 compute) -> fp8 Q/K/V outputs ----------------
__global__ __launch_bounds__(256, 2) void gemm_qkv(const u16* __restrict__ xnT,
                                                   const u16* __restrict__ wq_bf,
                                                   u8* __restrict__ outQ,
                                                   u8* __restrict__ outK,
                                                   u8* __restrict__ outV) {
  __shared__ __align__(16) char smem[65536];

  const int id = blockIdx.x;
  const int wg = (id & 7) * 192 + (id >> 3);
  const bool mode0 = (wg < 1024);
  int rt, ct;
  if (mode0) { rt = wg >> 3; ct = wg & 7; }
  else       { int w1 = wg - 1024; rt = w1 & 3; ct = w1 >> 2; }

  const char* Ab = mode0 ? (const char*)xnT + (size_t)rt * 131072
                         : (const char*)wq_bf + (size_t)(8 + rt) * 131072;
  const char* Bb = mode0 ? (const char*)wq_bf + (size_t)ct * 131072
                         : (const char*)xnT + (size_t)ct * 131072;

  const int t = threadIdx.x;
  const int lane = t & 63, w = t >> 6;
  const int q = lane & 31, hi = lane >> 5;
  const int rh = (w >> 1) * 64, ch = (w & 1) * 64;

  int soff[4];
  #pragma unroll
  for (int i = 0; i < 4; ++i) {
    int p = w*4096 + i*1024 + lane*16;
    int lrow = p >> 9, off = p & 511;
    int loff = off ^ ((lrow & 15) << 4);
    soff[i] = (lrow*4 + (loff >> 7)) * 1024 + (loff & 127);
  }

  #pragma unroll
  for (int i = 0; i < 4; ++i) {
    gload16(Ab + soff[i], smem +         w*4096 + i*1024);
    gload16(Bb + soff[i], smem + 16384 + w*4096 + i*1024);
  }

  f32x16 acc[2][2] = {};

  for (int kt = 0; kt < 8; ++kt) {
    asm volatile("s_waitcnt vmcnt(0)" ::: "memory");
    __syncthreads();
    const char* cur = smem + (kt & 1) * 32768;
    if (kt + 1 < 8) {
      char* nxt = smem + ((kt + 1) & 1) * 32768;
      #pragma unroll
      for (int i = 0; i < 4; ++i) {
        gload16(Ab + (kt+1)*128 + soff[i], nxt +         w*4096 + i*1024);
        gload16(Bb + (kt+1)*128 + soff[i], nxt + 16384 + w*4096 + i*1024);
      }
    }
    __builtin_amdgcn_s_setprio(1);
    #pragma unroll
    for (int ck = 0; ck < 4; ++ck) {
      short8 af0 = rd512(cur,         rh + q,      ck, hi);
      short8 af1 = rd512(cur,         rh + 32 + q, ck, hi);
      short8 bf0 = rd512(cur + 16384, ch + q,      ck, hi);
      short8 bf1 = rd512(cur + 16384, ch + 32 + q, ck, hi);
      acc[0][0] = __builtin_amdgcn_mfma_f32_32x32x16_bf16(af0, bf0, acc[0][0], 0, 0, 0);
      acc[0][1] = __builtin_amdgcn_mfma_f32_32x32x16_bf16(af0, bf1, acc[0][1], 0, 0, 0);
      acc[1][0] = __builtin_amdgcn_mfma_f32_32x32x16_bf16(af1, bf0, acc[1][0], 0, 0, 0);
      acc[1][1] = __builtin_amdgcn_mfma_f32_32x32x16_bf16(af1, bf1, acc[1][1], 0, 0, 0);
    }
    __builtin_amdgcn_s_setprio(0);
  }

  // epilogue: fp8 transpose via LDS, then 64B/thread coalesced stores
  __syncthreads();
  u8* Dt = (u8*)smem;   // [128][144] fp8
  #pragma unroll
  for (int r = 0; r < 16; ++r) {
    int ar = (r & 3) + 8*(r >> 2) + 4*hi;
    Dt[(rh +      ar) * 144 + ch +      q] = f2fp8(acc[0][0][r]);
    Dt[(rh +      ar) * 144 + ch + 32 + q] = f2fp8(acc[0][1][r]);
    Dt[(rh + 32 + ar) * 144 + ch +      q] = f2fp8(acc[1][0][r]);
    Dt[(rh + 32 + ar) * 144 + ch + 32 + q] = f2fp8(acc[1][1][r]);
  }
  __syncthreads();

  const int rl = t >> 1, hoff = (t & 1) * 64;
  uint4 buf[4];
  const uint4* s4 = reinterpret_cast<const uint4*>(&Dt[rl*144 + hoff]);
  #pragma unroll
  for (int e = 0; e < 4; ++e) buf[e] = s4[e];

  u8* gdst;
  if (mode0) {
    const int tok0 = rt * 128;
    const int b = tok0 >> 10, pix0 = tok0 & 1023;
    const int h = ct & 3;
    u8* base = (ct >= 4) ? outK : outQ;
    gdst = base + ((size_t)((b*NHEAD + h)) * NPIX + pix0 + rl) * HDIM + hoff;
  } else {
    const int m0 = rt * 128, tok0 = ct * 128;
    const int b = tok0 >> 10, pix0 = tok0 & 1023;
    gdst = outV + ((size_t)(b*CCH + m0 + rl)) * NPIX + pix0 + hoff;
  }
  uint4* g4 = reinterpret_cast<uint4*>(gdst);
  #pragma unroll
  for (int e = 0; e < 4; ++e) g4[e] = buf[e];
}

// ---------------- proj GEMM: dbuf-pipelined, fused residual + bias -> fp32 out ----------------
__global__ __launch_bounds__(256, 2) void gemm_proj(const u16* __restrict__ wp_bf,
                                                    const u16* __restrict__ attnO,
                                                    const float* __restrict__ xres,
                                                    const float* __restrict__ bias,
                                                    float* __restrict__ outF) {
  __shared__ __align__(16) char smem[65536];

  const int id = blockIdx.x;
  const int wg = (id & 7) * 64 + (id >> 3);
  const int rt = wg & 3, ct = wg >> 2;

  const char* Ab = (const char*)wp_bf + (size_t)rt * 131072;
  const char* Bb = (const char*)attnO + (size_t)ct * 131072;

  const int t = threadIdx.x;
  const int lane = t & 63, w = t >> 6;
  const int q = lane & 31, hi = lane >> 5;
  const int rh = (w >> 1) * 64, ch = (w & 1) * 64;

  int soff[4];
  #pragma unroll
  for (int i = 0; i < 4; ++i) {
    int p = w*4096 + i*1024 + lane*16;
    int lrow = p >> 9, off = p & 511;
    int loff = off ^ ((lrow & 15) << 4);
    soff[i] = (lrow*4 + (loff >> 7)) * 1024 + (loff & 127);
  }

  #pragma unroll
  for (int i = 0; i < 4; ++i) {
    gload16(Ab + soff[i], smem +         w*4096 + i*1024);
    gload16(Bb + soff[i], smem + 16384 + w*4096 + i*1024);
  }

  f32x16 acc[2][2] = {};

  for (int kt = 0; kt < 8; ++kt) {
    asm volatile("s_waitcnt vmcnt(0)" ::: "memory");
    __syncthreads();
    const char* cur = smem + (kt & 1) * 32768;
    if (kt + 1 < 8) {
      char* nxt = smem + ((kt + 1) & 1) * 32768;
      #pragma unroll
      for (int i = 0; i < 4; ++i) {
        gload16(Ab + (kt+1)*128 + soff[i], nxt +         w*4096 + i*1024);
        gload16(Bb + (kt+1)*128 + soff[i], nxt + 16384 + w*4096 + i*1024);
      }
    }
    __builtin_amdgcn_s_setprio(1);
    #pragma unroll
    for (int ck = 0; ck < 4; ++ck) {
      short8 af0 = rd512(cur,         rh + q,      ck, hi);
      short8 af1 = rd512(cur,         rh + 32 + q, ck, hi);
      short8 bf0 = rd512(cur + 16384, ch + q,      ck, hi);
      short8 bf1 = rd512(cur + 16384, ch + 32 + q, ck, hi);
      acc[0][0] = __builtin_amdgcn_mfma_f32_32x32x16_bf16(af0, bf0, acc[0][0], 0, 0, 0);
      acc[0][1] = __builtin_amdgcn_mfma_f32_32x32x16_bf16(af0, bf1, acc[0][1], 0, 0, 0);
      acc[1][0] = __builtin_amdgcn_mfma_f32_32x32x16_bf16(af1, bf0, acc[1][0], 0, 0, 0);
      acc[1][1] = __builtin_amdgcn_mfma_f32_32x32x16_bf16(af1, bf1, acc[1][1], 0, 0, 0);
    }
    __builtin_amdgcn_s_setprio(0);
  }

  const int m0 = rt * 128, tok0 = ct * 128;
  const int b = tok0 >> 10, pix0 = tok0 & 1023;
  #pragma unroll
  for (int r = 0; r < 16; ++r) {
    int ar = (r & 3) + 8*(r >> 2) + 4*hi;
    int m0r = m0 + rh + ar, m1r = m0 + rh + 32 + ar;
    size_t o00 = ((size_t)(b*CCH + m0r)) * NPIX + pix0 + ch + q;
    size_t o01 = o00 + 32;
    size_t o10 = ((size_t)(b*CCH + m1r)) * NPIX + pix0 + ch + q;
    size_t o11 = o10 + 32;
    outF[o00] = xres[o00] + acc[0][0][r] + bias[m0r];
    outF[o01] = xres[o01] + acc[0][1][r] + bias[m0r];
    outF[o10] = xres[o10] + acc[1][0][r] + bias[m1r];
    outF[o11] = xres[o11] + acc[1][1][r] + bias[m1r];
  }
}

// ---------------- Flash attention: fp8, in-block kv-split, 4 blocks/CU ----------------
// Block = 64 q-rows; waves: qsub = w&1 (32 q each), kvh = w>>1 (kv half of each 64-kv tile).
// Per wave per tile: 8 QK MFMA (32q x 32kv x 128ch) + 8 PV MFMA.
// Fixed-shift softmax => kv-half partials exactly summable; combined via LDS epilogue.
__global__ __launch_bounds__(256, 4) void attn_k(const u8* __restrict__ Qt,
                                                 const u8* __restrict__ Kt,
                                                 const u8* __restrict__ Vb,
                                                 u16* __restrict__ attnO) {
  int id = blockIdx.x;
  int swz = (id & 7) * 128 + (id >> 3);   // 1024 blocks, 8 XCDs; qt fastest -> L2 reuse
  const int qt = swz & 15;
  const int h  = (swz >> 4) & 3;
  const int b  = swz >> 6;
  const int bh = b * NHEAD + h;

  // K dbuf 2x8K @0 | V dbuf 2x8K @16384 | epilogue reuses [0,32768) + l @32768
  __shared__ __align__(16) char smem[33024];

  const int t = threadIdx.x;
  const int lane = t & 63, w = t >> 6;
  const int q = lane & 31, hi = lane >> 5;
  const int qsub = w & 1, kvh = w >> 1;

  const u8*   Qb    = Qt + ((size_t)bh * NPIX + qt*64 + qsub*32 + q) * HDIM;
  const char* Kbase = (const char*)Kt + (size_t)bh * NPIX * HDIM;
  const char* Vbase = (const char*)Vb + ((size_t)b*CCH + h*HDIM) * NPIX;

  // Q fragments: 8 fp8 (k = ck*16 + hi*8 + j)
  i64 qf[8];
  #pragma unroll
  for (int ck = 0; ck < 8; ++ck)
    qf[ck] = *reinterpret_cast<const i64*>(Qb + ck*16 + hi*8);

  // staging source offsets (pre-inverse-swizzled, linear LDS dest), 2x16B/thread/tensor
  int koff[2], voff[2];
  #pragma unroll
  for (int i = 0; i < 2; ++i) {
    int d = i*4096 + w*1024 + lane*16;   // 0..8191
    int r = d >> 7, x = d & 127;
    koff[i] = r*128 + (x ^ ((r & 15) << 3));
    int vc = 2*r + (x >> 6);
    voff[i] = vc*1024 + ((x & 63) ^ ((r & 7) << 3));
  }

  const int ksw  = (q & 15) << 3;
  const int krow = (kvh*32 + q) * 128;   // this wave's K rows
  const int vkv  = kvh * 32;             // kv base within V row's 64B half

  f32x16 of[4] = {};
  float l_run = 0.f;
  i64 pf[2];
  const float qs2 = 0.08838834764831845f * 1.44269504088896f;

  // prologue: K0->kb0, K1->kb1, V0->vb0 (K before V); full drain once
  #pragma unroll
  for (int i = 0; i < 2; ++i)
    gload16(Kbase + koff[i],        smem +        i*4096 + w*1024);
  #pragma unroll
  for (int i = 0; i < 2; ++i)
    gload16(Kbase + 8192 + koff[i], smem + 8192 + i*4096 + w*1024);
  #pragma unroll
  for (int i = 0; i < 2; ++i)
    gload16(Vbase + voff[i],        smem + 16384 + i*4096 + w*1024);
  asm volatile("s_waitcnt vmcnt(0)" ::: "memory");
  __syncthreads();

  // QK(0) + softmax(0)
  {
    f32x16 sn = {};
    #pragma unroll
    for (int ck = 0; ck < 8; ++ck) {
      const i64 kf = *reinterpret_cast<const i64*>(smem + krow + ((ck*16 + hi*8) ^ ksw));
      sn = __builtin_amdgcn_mfma_f32_32x32x16_fp8_fp8(kf, qf[ck], sn, 0, 0, 0);
    }
    l_run += softmax_pack16(sn, qs2, pf);
  }

  // main loop: iter tt = {QK_{tt+1} || PV_tt}, counted waits, raw barriers
  for (int tt = 0; tt < 16; ++tt) {
    asm volatile("s_waitcnt vmcnt(2)" ::: "memory");   // K(tt+1) landed; V(tt) may fly
    __builtin_amdgcn_s_barrier();

    const char* kcur = smem + (((tt+1) & 1) << 13);
    const char* vcur = smem + 16384 + ((tt & 1) << 13);

    // issue K first (older), then V
    if (tt + 2 < 16) {
      char* kd = smem + ((tt & 1) << 13);
      #pragma unroll
      for (int i = 0; i < 2; ++i)
        gload16(Kbase + (size_t)(tt+2)*8192 + koff[i], kd + i*4096 + w*1024);
    }
    if (tt + 1 < 16) {
      char* vd = smem + 16384 + (((tt+1) & 1) << 13);
      #pragma unroll
      for (int i = 0; i < 2; ++i)
        gload16(Vbase + (size_t)(tt+1)*64 + voff[i], vd + i*4096 + w*1024);
    }

    f32x16 sn = {};
    __builtin_amdgcn_s_setprio(1);
    if (tt + 1 < 16) {
      #pragma unroll
      for (int ck = 0; ck < 8; ++ck) {
        const i64 kf = *reinterpret_cast<const i64*>(kcur + krow + ((ck*16 + hi*8) ^ ksw));
        sn = __builtin_amdgcn_mfma_f32_32x32x16_fp8_fp8(kf, qf[ck], sn, 0, 0, 0);
      }
    }
    __builtin_amdgcn_s_setprio(0);

    // V(tt) wait: leave this iter's fresh loads in flight
    if (tt < 14)       asm volatile("s_waitcnt vmcnt(4)" ::: "memory");
    else if (tt == 14) asm volatile("s_waitcnt vmcnt(2)" ::: "memory");
    else               asm volatile("s_waitcnt vmcnt(0)" ::: "memory");
    __builtin_amdgcn_s_barrier();

    // PV(tt): this wave's 32-kv half
    __builtin_amdgcn_s_setprio(1);
    #pragma unroll
    for (int cg = 0; cg < 4; ++cg) {
      const int c = cg*32 + q;
      const char* vrow = vcur + (c >> 1)*128 + (c & 1)*64;
      const int vsw = ((c >> 1) & 7) << 3;
      #pragma unroll
      for (int kc = 0; kc < 2; ++kc) {
        const i64 vf = *reinterpret_cast<const i64*>(vrow + ((vkv + kc*16 + hi*8) ^ vsw));
        of[cg] = __builtin_amdgcn_mfma_f32_32x32x16_fp8_fp8(vf, pf[kc], of[cg], 0, 0, 0);
      }
    }
    __builtin_amdgcn_s_setprio(0);

    // softmax(tt+1)
    if (tt + 1 < 16)
      l_run += softmax_pack16(sn, qs2, pf);
  }

  // ---- epilogue: combine kv halves via LDS (K/V buffers dead) ----
  l_run += __shfl_xor(l_run, 32);   // full 32-kv sum per q for this kvh
  __syncthreads();
  float* exf = (float*)smem;              // [qsub][cg][r][lane] = 8192 f32 = 32KB
  float* exl = (float*)(smem + 32768);    // [qsub][q] = 64 f32

  if (kvh == 1) {
    #pragma unroll
    for (int cg = 0; cg < 4; ++cg)
      #pragma unroll
      for (int r = 0; r < 16; ++r)
        exf[qsub*4096 + cg*1024 + r*64 + lane] = of[cg][r];
    if (lane < 32) exl[qsub*32 + q] = l_run;
  }
  __syncthreads();
  if (kvh == 0) {
    const float inv = 1.f / (l_run + exl[qsub*32 + q]);
    u16* orow = attnO + ((size_t)(b*NPIX + qt*64 + qsub*32 + q)) * CCH + h*HDIM;
    #pragma unroll
    for (int cg = 0; cg < 4; ++cg) {
      #pragma unroll
      for (int u = 0; u < 8; ++u) {
        int c = cg*32 + ((2*u) & 3) + 8*(u >> 1) + 4*hi;
        float a0 = (of[cg][2*u]   + exf[qsub*4096 + cg*1024 + (2*u)*64   + lane]) * inv;
        float a1 = (of[cg][2*u+1] + exf[qsub*4096 + cg*1024 + (2*u+1)*64 + lane]) * inv;
        *reinterpret_cast<u32*>(&orow[c]) = (u32)f2bf(a0) | ((u32)f2bf(a1) << 16);
      }
    }
  }
}

// ---------------- launch ----------------
extern "C" void kernel_launch(void* const* d_in, const int* in_sizes, int n_in,
                              void* d_out, int out_size, void* d_ws, size_t ws_size,
                              hipStream_t stream) {
  const float* x     = (const float*)d_in[0];
  const float* gamma = (const float*)d_in[1];
  const float* beta  = (const float*)d_in[2];
  const float* wqkv  = (const float*)d_in[3];
  const float* wproj = (const float*)d_in[4];
  const float* bproj = (const float*)d_in[5];
  float* out = (float*)d_out;

  char* ws = (char*)d_ws;
  float* part   = (float*)ws;                          // 8 KB
  u16*   xnT    = (u16*)(ws + 8192);                   // 16 MB [16384][512] bf16
  u16*   wq_bf  = (u16*)(ws + 8192 + (16u<<20));       // 1.5 MB
  u16*   wp_bf  = (u16*)((char*)wq_bf + 1572864);      // 0.5 MB
  u8*    Qt     = (u8*)((char*)wp_bf + 524288);        // 8 MB fp8 [bh][1024][128]
  u8*    Kt     = (u8*)((char*)Qt + (8u<<20));         // 8 MB fp8
  u8*    Vb     = (u8*)((char*)Kt + (8u<<20));         // 8 MB fp8 [b*512+m][1024]
  u16*   attnO  = (u16*)((char*)Vb + (8u<<20));        // 16 MB bf16 [16384][512]

  gn_stats_k<<<dim3(1024), dim3(256), 0, stream>>>(x, part);
  gn_apply_t<<<dim3(16, 8, BATCH), dim3(256), 0, stream>>>(x, gamma, beta, part, xnT);
  f2bf_all<<<dim3(1024), dim3(256), 0, stream>>>(wqkv, wproj, wq_bf, wp_bf);

  gemm_qkv<<<dim3(1536), dim3(256), 0, stream>>>(xnT, wq_bf, Qt, Kt, Vb);

  attn_k<<<dim3(1024), dim3(256), 0, stream>>>(Qt, Kt, Vb, attnO);

  gemm_proj<<<dim3(512), dim3(256), 0, stream>>>(wp_bf, attnO, x, bproj, out);
}

// Round 15
// 114.101 us; speedup vs baseline: 1.0659x; 1.0659x over previous
//
#include <hip/hip_runtime.h>
#include <stdint.h>

typedef unsigned char u8;
typedef unsigned short u16;
typedef unsigned int u32;
typedef long long i64;
typedef __attribute__((ext_vector_type(8))) short short8;
typedef __attribute__((ext_vector_type(4))) float f32x4;
typedef __attribute__((ext_vector_type(16))) float f32x16;

#define BATCH 16
#define CCH   512
#define NPIX  1024
#define NGRP  8
#define CPG   64
#define NHEAD 4
#define HDIM  128

__device__ __forceinline__ u16 f2bf(float f) {
  union { float f; u32 u; } v; v.f = f;
  u32 u = v.u;
  u32 r = (u + 0x7FFFu + ((u >> 16) & 1u)) >> 16;
  return (u16)r;
}
__device__ __forceinline__ u8 f2fp8(float f) {
  return (u8)(__builtin_amdgcn_cvt_pk_fp8_f32(f, 0.f, 0, false) & 0xff);
}
__device__ __forceinline__ u32 pack4_fp8(float a, float b, float c, float d) {
  u32 w = (u32)__builtin_amdgcn_cvt_pk_fp8_f32(a, b, 0, false);
  w = (u32)__builtin_amdgcn_cvt_pk_fp8_f32(c, d, (int)w, true);
  return w;
}

// async global->LDS, 16B per lane; dest = wave-uniform base + lane*16
__device__ __forceinline__ void gload16(const void* g, void* l) {
  typedef __attribute__((address_space(3))) u32 L;
  typedef __attribute__((address_space(1))) const u32 G;
  __builtin_amdgcn_global_load_lds((G*)(uintptr_t)g, (L*)(u32)(uintptr_t)l, 16, 0, 0);
}

#define PLSWAP(a, b) asm("v_permlane32_swap_b32 %0, %1" : "+v"(a), "+v"(b))

// 512B-pitch swizzled LDS fragment read (rows packed 4-per-512B, 4-bit XOR) - bf16 GEMM
__device__ __forceinline__ short8 rd512(const char* base, int r, int ck, int hi) {
  int byte = ((r >> 2) * 512) +
             ((((r & 3) * 128) + ck * 32 + hi * 16) ^ (((r >> 2) & 15) << 4));
  return *reinterpret_cast<const short8*>(base + byte);
}

// ---------------- GroupNorm partial stats ----------------
__global__ void gn_stats_k(const float* __restrict__ x, float* __restrict__ part) {
  int bg = blockIdx.x >> 3, sl = blockIdx.x & 7;
  const float* p = x + (size_t)bg * (CPG * NPIX) + sl * 8192;
  float s = 0.f, ss = 0.f;
  for (int i = threadIdx.x; i < 2048; i += 256) {
    float4 v = reinterpret_cast<const float4*>(p)[i];
    s  += v.x + v.y + v.z + v.w;
    ss += v.x*v.x + v.y*v.y + v.z*v.z + v.w*v.w;
  }
  for (int o = 32; o > 0; o >>= 1) { s += __shfl_down(s, o); ss += __shfl_down(ss, o); }
  __shared__ float sh[8];
  int wid = threadIdx.x >> 6;
  if ((threadIdx.x & 63) == 0) { sh[wid*2] = s; sh[wid*2+1] = ss; }
  __syncthreads();
  if (threadIdx.x == 0) {
    part[blockIdx.x*2]   = sh[0]+sh[2]+sh[4]+sh[6];
    part[blockIdx.x*2+1] = sh[1]+sh[3]+sh[5]+sh[7];
  }
}

// ---------------- GroupNorm apply + transpose -> token-major bf16 xnT[tok][512] ----------------
__global__ __launch_bounds__(256) void gn_apply_t(const float* __restrict__ x,
                                                  const float* __restrict__ gamma,
                                                  const float* __restrict__ beta,
                                                  const float* __restrict__ part,
                                                  u16* __restrict__ xnT) {
  const int p0 = blockIdx.x * 64;
  const int c0 = blockIdx.y * 64;
  const int b  = blockIdx.z;
  __shared__ float lt[64][66];

  const int bg = b * NGRP + (c0 >> 6);
  float s = 0.f, ss = 0.f;
  #pragma unroll
  for (int k2 = 0; k2 < 8; ++k2) { s += part[(bg*8 + k2)*2]; ss += part[(bg*8 + k2)*2 + 1]; }
  const float invn = 1.f / (float)(CPG * NPIX);
  const float mean = s * invn;
  const float rstd = rsqrtf(ss * invn - mean * mean + 1e-5f);

  const int t = threadIdx.x;
  #pragma unroll
  for (int pass = 0; pass < 4; ++pass) {
    int c   = c0 + (t >> 4) + pass * 16;
    int pix = p0 + (t & 15) * 4;
    float ga = gamma[c] * rstd;
    float be = beta[c] - mean * ga;
    float4 v = *reinterpret_cast<const float4*>(&x[((size_t)(b*CCH + c)) * NPIX + pix]);
    int pl = (t & 15) * 4, cl = (t >> 4) + pass * 16;
    lt[pl+0][cl] = v.x*ga + be;
    lt[pl+1][cl] = v.y*ga + be;
    lt[pl+2][cl] = v.z*ga + be;
    lt[pl+3][cl] = v.w*ga + be;
  }
  __syncthreads();
  const int pl = t >> 2, cq = (t & 3) * 16;
  u32 wbuf[8];
  #pragma unroll
  for (int e = 0; e < 8; ++e) {
    u16 lo = f2bf(lt[pl][cq + e*2]);
    u16 hi = f2bf(lt[pl][cq + e*2 + 1]);
    wbuf[e] = (u32)lo | ((u32)hi << 16);
  }
  u32* dst = (u32*)&xnT[((size_t)(b*NPIX + p0 + pl)) * CCH + c0 + cq];
  #pragma unroll
  for (int e = 0; e < 8; ++e) dst[e] = wbuf[e];
}

// ---------------- fp32 -> bf16 weights ----------------
__global__ void f2bf_all(const float* __restrict__ wqkv, const float* __restrict__ wproj,
                         u16* __restrict__ wq, u16* __restrict__ wp) {
  int i = blockIdx.x * 256 + threadIdx.x;
  float4 v; u16* dst;
  if (i < 196608) {
    v = reinterpret_cast<const float4*>(wqkv)[i];
    dst = wq + (size_t)i * 4;
  } else {
    v = reinterpret_cast<const float4*>(wproj)[i - 196608];
    dst = wp + (size_t)(i - 196608) * 4;
  }
  u32 lo = (u32)f2bf(v.x) | ((u32)f2bf(v.y) << 16);
  u32 hi = (u32)f2bf(v.z) | ((u32)f2bf(v.w) << 16);
  *reinterpret_cast<uint2*>(dst) = make_uint2(lo, hi);
}

// ---------------- merged QKV GEMM (bf16 compute) -> fp8 Q/K/V outputs ----------------
__global__ __launch_bounds__(256, 2) void gemm_qkv(const u16* __restrict__ xnT,
                                                   const u16* __restrict__ wq_bf,
                                                   u8* __restrict__ outQ,
                                                   u8* __restrict__ outK,
                                                   u8* __restrict__ outV) {
  __shared__ __align__(16) char smem[65536];

  const int id = blockIdx.x;
  const int wg = (id & 7) * 192 + (id >> 3);
  const bool mode0 = (wg < 1024);
  int rt, ct;
  if (mode0) { rt = wg >> 3; ct = wg & 7; }
  else       { int w1 = wg - 1024; rt = w1 & 3; ct = w1 >> 2; }

  const char* Ab = mode0 ? (const char*)xnT + (size_t)rt * 131072
                         : (const char*)wq_bf + (size_t)(8 + rt) * 131072;
  const char* Bb = mode0 ? (const char*)wq_bf + (size_t)ct * 131072
                         : (const char*)xnT + (size_t)ct * 131072;

  const int t = threadIdx.x;
  const int lane = t & 63, w = t >> 6;
  const int q = lane & 31, hi = lane >> 5;
  const int rh = (w >> 1) * 64, ch = (w & 1) * 64;

  int soff[4];
  #pragma unroll
  for (int i = 0; i < 4; ++i) {
    int p = w*4096 + i*1024 + lane*16;
    int lrow = p >> 9, off = p & 511;
    int loff = off ^ ((lrow & 15) << 4);
    soff[i] = (lrow*4 + (loff >> 7)) * 1024 + (loff & 127);
  }

  #pragma unroll
  for (int i = 0; i < 4; ++i) {
    gload16(Ab + soff[i], smem +         w*4096 + i*1024);
    gload16(Bb + soff[i], smem + 16384 + w*4096 + i*1024);
  }

  f32x16 acc[2][2] = {};

  for (int kt = 0; kt < 8; ++kt) {
    asm volatile("s_waitcnt vmcnt(0)" ::: "memory");
    __syncthreads();
    const char* cur = smem + (kt & 1) * 32768;
    if (kt + 1 < 8) {
      char* nxt = smem + ((kt + 1) & 1) * 32768;
      #pragma unroll
      for (int i = 0; i < 4; ++i) {
        gload16(Ab + (kt+1)*128 + soff[i], nxt +         w*4096 + i*1024);
        gload16(Bb + (kt+1)*128 + soff[i], nxt + 16384 + w*4096 + i*1024);
      }
    }
    __builtin_amdgcn_s_setprio(1);
    #pragma unroll
    for (int ck = 0; ck < 4; ++ck) {
      short8 af0 = rd512(cur,         rh + q,      ck, hi);
      short8 af1 = rd512(cur,         rh + 32 + q, ck, hi);
      short8 bf0 = rd512(cur + 16384, ch + q,      ck, hi);
      short8 bf1 = rd512(cur + 16384, ch + 32 + q, ck, hi);
      acc[0][0] = __builtin_amdgcn_mfma_f32_32x32x16_bf16(af0, bf0, acc[0][0], 0, 0, 0);
      acc[0][1] = __builtin_amdgcn_mfma_f32_32x32x16_bf16(af0, bf1, acc[0][1], 0, 0, 0);
      acc[1][0] = __builtin_amdgcn_mfma_f32_32x32x16_bf16(af1, bf0, acc[1][0], 0, 0, 0);
      acc[1][1] = __builtin_amdgcn_mfma_f32_32x32x16_bf16(af1, bf1, acc[1][1], 0, 0, 0);
    }
    __builtin_amdgcn_s_setprio(0);
  }

  // epilogue: fp8 transpose via LDS, then 64B/thread coalesced stores
  __syncthreads();
  u8* Dt = (u8*)smem;   // [128][144] fp8
  #pragma unroll
  for (int r = 0; r < 16; ++r) {
    int ar = (r & 3) + 8*(r >> 2) + 4*hi;
    Dt[(rh +      ar) * 144 + ch +      q] = f2fp8(acc[0][0][r]);
    Dt[(rh +      ar) * 144 + ch + 32 + q] = f2fp8(acc[0][1][r]);
    Dt[(rh + 32 + ar) * 144 + ch +      q] = f2fp8(acc[1][0][r]);
    Dt[(rh + 32 + ar) * 144 + ch + 32 + q] = f2fp8(acc[1][1][r]);
  }
  __syncthreads();

  const int rl = t >> 1, hoff = (t & 1) * 64;
  uint4 buf[4];
  const uint4* s4 = reinterpret_cast<const uint4*>(&Dt[rl*144 + hoff]);
  #pragma unroll
  for (int e = 0; e < 4; ++e) buf[e] = s4[e];

  u8* gdst;
  if (mode0) {
    const int tok0 = rt * 128;
    const int b = tok0 >> 10, pix0 = tok0 & 1023;
    const int h = ct & 3;
    u8* base = (ct >= 4) ? outK : outQ;
    gdst = base + ((size_t)((b*NHEAD + h)) * NPIX + pix0 + rl) * HDIM + hoff;
  } else {
    const int m0 = rt * 128, tok0 = ct * 128;
    const int b = tok0 >> 10, pix0 = tok0 & 1023;
    gdst = outV + ((size_t)(b*CCH + m0 + rl)) * NPIX + pix0 + hoff;
  }
  uint4* g4 = reinterpret_cast<uint4*>(gdst);
  #pragma unroll
  for (int e = 0; e < 4; ++e) g4[e] = buf[e];
}

// ---------------- proj GEMM: dbuf-pipelined, fused residual + bias -> fp32 out ----------------
__global__ __launch_bounds__(256, 2) void gemm_proj(const u16* __restrict__ wp_bf,
                                                    const u16* __restrict__ attnO,
                                                    const float* __restrict__ xres,
                                                    const float* __restrict__ bias,
                                                    float* __restrict__ outF) {
  __shared__ __align__(16) char smem[65536];

  const int id = blockIdx.x;
  const int wg = (id & 7) * 64 + (id >> 3);
  const int rt = wg & 3, ct = wg >> 2;

  const char* Ab = (const char*)wp_bf + (size_t)rt * 131072;
  const char* Bb = (const char*)attnO + (size_t)ct * 131072;

  const int t = threadIdx.x;
  const int lane = t & 63, w = t >> 6;
  const int q = lane & 31, hi = lane >> 5;
  const int rh = (w >> 1) * 64, ch = (w & 1) * 64;

  int soff[4];
  #pragma unroll
  for (int i = 0; i < 4; ++i) {
    int p = w*4096 + i*1024 + lane*16;
    int lrow = p >> 9, off = p & 511;
    int loff = off ^ ((lrow & 15) << 4);
    soff[i] = (lrow*4 + (loff >> 7)) * 1024 + (loff & 127);
  }

  #pragma unroll
  for (int i = 0; i < 4; ++i) {
    gload16(Ab + soff[i], smem +         w*4096 + i*1024);
    gload16(Bb + soff[i], smem + 16384 + w*4096 + i*1024);
  }

  f32x16 acc[2][2] = {};

  for (int kt = 0; kt < 8; ++kt) {
    asm volatile("s_waitcnt vmcnt(0)" ::: "memory");
    __syncthreads();
    const char* cur = smem + (kt & 1) * 32768;
    if (kt + 1 < 8) {
      char* nxt = smem + ((kt + 1) & 1) * 32768;
      #pragma unroll
      for (int i = 0; i < 4; ++i) {
        gload16(Ab + (kt+1)*128 + soff[i], nxt +         w*4096 + i*1024);
        gload16(Bb + (kt+1)*128 + soff[i], nxt + 16384 + w*4096 + i*1024);
      }
    }
    __builtin_amdgcn_s_setprio(1);
    #pragma unroll
    for (int ck = 0; ck < 4; ++ck) {
      short8 af0 = rd512(cur,         rh + q,      ck, hi);
      short8 af1 = rd512(cur,         rh + 32 + q, ck, hi);
      short8 bf0 = rd512(cur + 16384, ch + q,      ck, hi);
      short8 bf1 = rd512(cur + 16384, ch + 32 + q, ck, hi);
      acc[0][0] = __builtin_amdgcn_mfma_f32_32x32x16_bf16(af0, bf0, acc[0][0], 0, 0, 0);
      acc[0][1] = __builtin_amdgcn_mfma_f32_32x32x16_bf16(af0, bf1, acc[0][1], 0, 0, 0);
      acc[1][0] = __builtin_amdgcn_mfma_f32_32x32x16_bf16(af1, bf0, acc[1][0], 0, 0, 0);
      acc[1][1] = __builtin_amdgcn_mfma_f32_32x32x16_bf16(af1, bf1, acc[1][1], 0, 0, 0);
    }
    __builtin_amdgcn_s_setprio(0);
  }

  const int m0 = rt * 128, tok0 = ct * 128;
  const int b = tok0 >> 10, pix0 = tok0 & 1023;
  #pragma unroll
  for (int r = 0; r < 16; ++r) {
    int ar = (r & 3) + 8*(r >> 2) + 4*hi;
    int m0r = m0 + rh + ar, m1r = m0 + rh + 32 + ar;
    size_t o00 = ((size_t)(b*CCH + m0r)) * NPIX + pix0 + ch + q;
    size_t o01 = o00 + 32;
    size_t o10 = ((size_t)(b*CCH + m1r)) * NPIX + pix0 + ch + q;
    size_t o11 = o10 + 32;
    outF[o00] = xres[o00] + acc[0][0][r] + bias[m0r];
    outF[o01] = xres[o01] + acc[0][1][r] + bias[m0r];
    outF[o10] = xres[o10] + acc[1][0][r] + bias[m1r];
    outF[o11] = xres[o11] + acc[1][1][r] + bias[m1r];
  }
}

// ---------------- Flash attention: fp8, R11 structure (proven 49.8 us) ----------------
__global__ __launch_bounds__(256, 2) void attn_k(const u8* __restrict__ Qt,
                                                 const u8* __restrict__ Kt,
                                                 const u8* __restrict__ Vb,
                                                 u16* __restrict__ attnO) {
  int id = blockIdx.x;
  int swz = (id & 7) * 64 + (id >> 3);
  const int qt = swz & 7;
  const int h  = (swz >> 3) & 3;
  const int b  = swz >> 5;
  const int bh = b * NHEAD + h;

  __shared__ __align__(16) char smem[32768];  // K dbuf 2x8K @0 | V dbuf 2x8K @16384

  const int t = threadIdx.x;
  const int lane = t & 63, w = t >> 6;
  const int q = lane & 31, hi = lane >> 5;

  const u8*   Qb    = Qt + ((size_t)bh * NPIX + qt*128 + w*32 + q) * HDIM;
  const char* Kbase = (const char*)Kt + (size_t)bh * NPIX * HDIM;
  const char* Vbase = (const char*)Vb + ((size_t)b*CCH + h*HDIM) * NPIX;

  i64 qf[8];
  #pragma unroll
  for (int ck = 0; ck < 8; ++ck)
    qf[ck] = *reinterpret_cast<const i64*>(Qb + ck*16 + hi*8);

  int koff[2], voff[2];
  #pragma unroll
  for (int i = 0; i < 2; ++i) {
    int d = i*4096 + w*1024 + lane*16;
    int r = d >> 7, x = d & 127;
    koff[i] = r*128 + (x ^ ((r & 15) << 3));
    int vc = 2*r + (x >> 6);
    voff[i] = vc*1024 + ((x & 63) ^ ((r & 7) << 3));
  }

  const int ksw = (q & 15) << 3;

  f32x16 of[4] = {};
  float l_run = 0.f;
  i64 pf[4];
  const float qs2 = 0.08838834764831845f * 1.44269504088896f;

  #pragma unroll
  for (int i = 0; i < 2; ++i)
    gload16(Kbase + koff[i],        smem +        i*4096 + w*1024);
  #pragma unroll
  for (int i = 0; i < 2; ++i)
    gload16(Kbase + 8192 + koff[i], smem + 8192 + i*4096 + w*1024);
  #pragma unroll
  for (int i = 0; i < 2; ++i)
    gload16(Vbase + voff[i],        smem + 16384 + i*4096 + w*1024);
  asm volatile("s_waitcnt vmcnt(0)" ::: "memory");
  __syncthreads();

  {
    f32x16 sn0 = {}, sn1 = {};
    #pragma unroll
    for (int ck = 0; ck < 8; ++ck) {
      const i64 kf0 = *reinterpret_cast<const i64*>(smem + q*128      + ((ck*16 + hi*8) ^ ksw));
      const i64 kf1 = *reinterpret_cast<const i64*>(smem + (32+q)*128 + ((ck*16 + hi*8) ^ ksw));
      sn0 = __builtin_amdgcn_mfma_f32_32x32x16_fp8_fp8(kf0, qf[ck], sn0, 0, 0, 0);
      sn1 = __builtin_amdgcn_mfma_f32_32x32x16_fp8_fp8(kf1, qf[ck], sn1, 0, 0, 0);
    }
    float ps = 0.f;
    float p[16];
    #pragma unroll
    for (int g = 0; g < 2; ++g) {
      const f32x16& sn = g ? sn1 : sn0;
      #pragma unroll
      for (int r = 0; r < 16; ++r) { p[r] = exp2f(sn[r] * qs2); ps += p[r]; }
      u32 pkl0 = pack4_fp8(p[0], p[1], p[2], p[3]);
      u32 pkh0 = pack4_fp8(p[4], p[5], p[6], p[7]);
      u32 pkl1 = pack4_fp8(p[8], p[9], p[10], p[11]);
      u32 pkh1 = pack4_fp8(p[12], p[13], p[14], p[15]);
      PLSWAP(pkl0, pkh0);
      PLSWAP(pkl1, pkh1);
      pf[g*2]   = (i64)(((unsigned long long)pkh0 << 32) | pkl0);
      pf[g*2+1] = (i64)(((unsigned long long)pkh1 << 32) | pkl1);
    }
    ps += __shfl_xor(ps, 32);
    l_run += ps;
  }

  for (int tt = 0; tt < 16; ++tt) {
    asm volatile("s_waitcnt vmcnt(2)" ::: "memory");
    __builtin_amdgcn_s_barrier();

    const char* kcur = smem + (((tt+1) & 1) << 13);
    const char* vcur = smem + 16384 + ((tt & 1) << 13);

    if (tt + 2 < 16) {
      char* kd = smem + ((tt & 1) << 13);
      #pragma unroll
      for (int i = 0; i < 2; ++i)
        gload16(Kbase + (size_t)(tt+2)*8192 + koff[i], kd + i*4096 + w*1024);
    }
    if (tt + 1 < 16) {
      char* vd = smem + 16384 + (((tt+1) & 1) << 13);
      #pragma unroll
      for (int i = 0; i < 2; ++i)
        gload16(Vbase + (size_t)(tt+1)*64 + voff[i], vd + i*4096 + w*1024);
    }

    f32x16 sn0 = {}, sn1 = {};
    __builtin_amdgcn_s_setprio(1);
    if (tt + 1 < 16) {
      #pragma unroll
      for (int ck = 0; ck < 8; ++ck) {
        const i64 kf0 = *reinterpret_cast<const i64*>(kcur + q*128      + ((ck*16 + hi*8) ^ ksw));
        const i64 kf1 = *reinterpret_cast<const i64*>(kcur + (32+q)*128 + ((ck*16 + hi*8) ^ ksw));
        sn0 = __builtin_amdgcn_mfma_f32_32x32x16_fp8_fp8(kf0, qf[ck], sn0, 0, 0, 0);
        sn1 = __builtin_amdgcn_mfma_f32_32x32x16_fp8_fp8(kf1, qf[ck], sn1, 0, 0, 0);
      }
    }
    __builtin_amdgcn_s_setprio(0);

    if (tt < 14)       asm volatile("s_waitcnt vmcnt(4)" ::: "memory");
    else if (tt == 14) asm volatile("s_waitcnt vmcnt(2)" ::: "memory");
    else               asm volatile("s_waitcnt vmcnt(0)" ::: "memory");
    __builtin_amdgcn_s_barrier();

    __builtin_amdgcn_s_setprio(1);
    #pragma unroll
    for (int cg = 0; cg < 4; ++cg) {
      const int c = cg*32 + q;
      const char* vrow = vcur + (c >> 1)*128 + (c & 1)*64;
      const int vsw = ((c >> 1) & 7) << 3;
      #pragma unroll
      for (int kc = 0; kc < 4; ++kc) {
        const i64 vf = *reinterpret_cast<const i64*>(vrow + ((kc*16 + hi*8) ^ vsw));
        of[cg] = __builtin_amdgcn_mfma_f32_32x32x16_fp8_fp8(vf, pf[kc], of[cg], 0, 0, 0);
      }
    }
    __builtin_amdgcn_s_setprio(0);

    if (tt + 1 < 16) {
      float ps = 0.f;
      float p[16];
      #pragma unroll
      for (int g = 0; g < 2; ++g) {
        const f32x16& sn = g ? sn1 : sn0;
        #pragma unroll
        for (int r = 0; r < 16; ++r) { p[r] = exp2f(sn[r] * qs2); ps += p[r]; }
        u32 pkl0 = pack4_fp8(p[0], p[1], p[2], p[3]);
        u32 pkh0 = pack4_fp8(p[4], p[5], p[6], p[7]);
        u32 pkl1 = pack4_fp8(p[8], p[9], p[10], p[11]);
        u32 pkh1 = pack4_fp8(p[12], p[13], p[14], p[15]);
        PLSWAP(pkl0, pkh0);
        PLSWAP(pkl1, pkh1);
        pf[g*2]   = (i64)(((unsigned long long)pkh0 << 32) | pkl0);
        pf[g*2+1] = (i64)(((unsigned long long)pkh1 << 32) | pkl1);
      }
      ps += __shfl_xor(ps, 32);
      l_run += ps;
    }
  }

  float inv = 1.f / l_run;
  u16* orow = attnO + ((size_t)(b*NPIX + qt*128 + w*32 + q)) * CCH + h*HDIM;
  #pragma unroll
  for (int cg = 0; cg < 4; ++cg) {
    #pragma unroll
    for (int u = 0; u < 8; ++u) {
      int c = cg*32 + ((2*u) & 3) + 8*(u >> 1) + 4*hi;
      u32 pk = (u32)f2bf(of[cg][2*u] * inv) | ((u32)f2bf(of[cg][2*u+1] * inv) << 16);
      *reinterpret_cast<u32*>(&orow[c]) = pk;
    }
  }
}

// ---------------- launch ----------------
extern "C" void kernel_launch(void* const* d_in, const int* in_sizes, int n_in,
                              void* d_out, int out_size, void* d_ws, size_t ws_size,
                              hipStream_t stream) {
  const float* x     = (const float*)d_in[0];
  const float* gamma = (const float*)d_in[1];
  const float* beta  = (const float*)d_in[2];
  const float* wqkv  = (const float*)d_in[3];
  const float* wproj = (const float*)d_in[4];
  const float* bproj = (const float*)d_in[5];
  float* out = (float*)d_out;

  char* ws = (char*)d_ws;
  float* part   = (float*)ws;                          // 8 KB
  u16*   xnT    = (u16*)(ws + 8192);                   // 16 MB [16384][512] bf16
  u16*   wq_bf  = (u16*)(ws + 8192 + (16u<<20));       // 1.5 MB
  u16*   wp_bf  = (u16*)((char*)wq_bf + 1572864);      // 0.5 MB
  u8*    Qt     = (u8*)((char*)wp_bf + 524288);        // 8 MB fp8 [bh][1024][128]
  u8*    Kt     = (u8*)((char*)Qt + (8u<<20));         // 8 MB fp8
  u8*    Vb     = (u8*)((char*)Kt + (8u<<20));         // 8 MB fp8 [b*512+m][1024]
  u16*   attnO  = (u16*)((char*)Vb + (8u<<20));        // 16 MB bf16 [16384][512]

  gn_stats_k<<<dim3(1024), dim3(256), 0, stream>>>(x, part);
  gn_apply_t<<<dim3(16, 8, BATCH), dim3(256), 0, stream>>>(x, gamma, beta, part, xnT);
  f2bf_all<<<dim3(1024), dim3(256), 0, stream>>>(wqkv, wproj, wq_bf, wp_bf);

  gemm_qkv<<<dim3(1536), dim3(256), 0, stream>>>(xnT, wq_bf, Qt, Kt, Vb);

  attn_k<<<dim3(512), dim3(256), 0, stream>>>(Qt, Kt, Vb, attnO);

  gemm_proj<<<dim3(512), dim3(256), 0, stream>>>(wp_bf, attnO, x, bproj, out);
}

// Round 16
// 110.403 us; speedup vs baseline: 1.1016x; 1.0335x over previous
//
#include <hip/hip_runtime.h>
#include <stdint.h>

typedef unsigned char u8;
typedef unsigned short u16;
typedef unsigned int u32;
typedef long long i64;
typedef __attribute__((ext_vector_type(8))) short short8;
typedef __attribute__((ext_vector_type(4))) float f32x4;
typedef __attribute__((ext_vector_type(16))) float f32x16;

#define BATCH 16
#define CCH   512
#define NPIX  1024
#define NGRP  8
#define CPG   64
#define NHEAD 4
#define HDIM  128

__device__ __forceinline__ u16 f2bf(float f) {
  union { float f; u32 u; } v; v.f = f;
  u32 u = v.u;
  u32 r = (u + 0x7FFFu + ((u >> 16) & 1u)) >> 16;
  return (u16)r;
}
__device__ __forceinline__ u8 f2fp8(float f) {
  return (u8)(__builtin_amdgcn_cvt_pk_fp8_f32(f, 0.f, 0, false) & 0xff);
}
__device__ __forceinline__ u32 pack4_fp8(float a, float b, float c, float d) {
  u32 w = (u32)__builtin_amdgcn_cvt_pk_fp8_f32(a, b, 0, false);
  w = (u32)__builtin_amdgcn_cvt_pk_fp8_f32(c, d, (int)w, true);
  return w;
}

// async global->LDS, 16B per lane; dest = wave-uniform base + lane*16
__device__ __forceinline__ void gload16(const void* g, void* l) {
  typedef __attribute__((address_space(3))) u32 L;
  typedef __attribute__((address_space(1))) const u32 G;
  __builtin_amdgcn_global_load_lds((G*)(uintptr_t)g, (L*)(u32)(uintptr_t)l, 16, 0, 0);
}

#define PLSWAP(a, b) asm("v_permlane32_swap_b32 %0, %1" : "+v"(a), "+v"(b))

// 512B-pitch swizzled LDS fragment read (rows packed 4-per-512B, 4-bit XOR) - bf16 GEMM
__device__ __forceinline__ short8 rd512(const char* base, int r, int ck, int hi) {
  int byte = ((r >> 2) * 512) +
             ((((r & 3) * 128) + ck * 32 + hi * 16) ^ (((r >> 2) & 15) << 4));
  return *reinterpret_cast<const short8*>(base + byte);
}

// ---------------- GroupNorm partial stats (blocks 0..1023) + weight conversion (1024..2047) ----------------
__global__ void gn_stats_wconv(const float* __restrict__ x, float* __restrict__ part,
                               const float* __restrict__ wqkv, const float* __restrict__ wproj,
                               u16* __restrict__ wq, u16* __restrict__ wp) {
  __shared__ float sh[8];
  if (blockIdx.x >= 1024) {
    int i = (blockIdx.x - 1024) * 256 + threadIdx.x;
    float4 v; u16* dst;
    if (i < 196608) {
      v = reinterpret_cast<const float4*>(wqkv)[i];
      dst = wq + (size_t)i * 4;
    } else {
      v = reinterpret_cast<const float4*>(wproj)[i - 196608];
      dst = wp + (size_t)(i - 196608) * 4;
    }
    u32 lo = (u32)f2bf(v.x) | ((u32)f2bf(v.y) << 16);
    u32 hi = (u32)f2bf(v.z) | ((u32)f2bf(v.w) << 16);
    *reinterpret_cast<uint2*>(dst) = make_uint2(lo, hi);
    return;
  }
  int bg = blockIdx.x >> 3, sl = blockIdx.x & 7;
  const float* p = x + (size_t)bg * (CPG * NPIX) + sl * 8192;
  float s = 0.f, ss = 0.f;
  for (int i = threadIdx.x; i < 2048; i += 256) {
    float4 v = reinterpret_cast<const float4*>(p)[i];
    s  += v.x + v.y + v.z + v.w;
    ss += v.x*v.x + v.y*v.y + v.z*v.z + v.w*v.w;
  }
  for (int o = 32; o > 0; o >>= 1) { s += __shfl_down(s, o); ss += __shfl_down(ss, o); }
  int wid = threadIdx.x >> 6;
  if ((threadIdx.x & 63) == 0) { sh[wid*2] = s; sh[wid*2+1] = ss; }
  __syncthreads();
  if (threadIdx.x == 0) {
    part[blockIdx.x*2]   = sh[0]+sh[2]+sh[4]+sh[6];
    part[blockIdx.x*2+1] = sh[1]+sh[3]+sh[5]+sh[7];
  }
}

// ---------------- GroupNorm apply + transpose -> token-major bf16 xnT[tok][512] ----------------
__global__ __launch_bounds__(256) void gn_apply_t(const float* __restrict__ x,
                                                  const float* __restrict__ gamma,
                                                  const float* __restrict__ beta,
                                                  const float* __restrict__ part,
                                                  u16* __restrict__ xnT) {
  const int p0 = blockIdx.x * 64;
  const int c0 = blockIdx.y * 64;
  const int b  = blockIdx.z;
  __shared__ float lt[64][66];

  const int bg = b * NGRP + (c0 >> 6);
  float s = 0.f, ss = 0.f;
  #pragma unroll
  for (int k2 = 0; k2 < 8; ++k2) { s += part[(bg*8 + k2)*2]; ss += part[(bg*8 + k2)*2 + 1]; }
  const float invn = 1.f / (float)(CPG * NPIX);
  const float mean = s * invn;
  const float rstd = rsqrtf(ss * invn - mean * mean + 1e-5f);

  const int t = threadIdx.x;
  #pragma unroll
  for (int pass = 0; pass < 4; ++pass) {
    int c   = c0 + (t >> 4) + pass * 16;
    int pix = p0 + (t & 15) * 4;
    float ga = gamma[c] * rstd;
    float be = beta[c] - mean * ga;
    float4 v = *reinterpret_cast<const float4*>(&x[((size_t)(b*CCH + c)) * NPIX + pix]);
    int pl = (t & 15) * 4, cl = (t >> 4) + pass * 16;
    lt[pl+0][cl] = v.x*ga + be;
    lt[pl+1][cl] = v.y*ga + be;
    lt[pl+2][cl] = v.z*ga + be;
    lt[pl+3][cl] = v.w*ga + be;
  }
  __syncthreads();
  const int pl = t >> 2, cq = (t & 3) * 16;
  u32 wbuf[8];
  #pragma unroll
  for (int e = 0; e < 8; ++e) {
    u16 lo = f2bf(lt[pl][cq + e*2]);
    u16 hi = f2bf(lt[pl][cq + e*2 + 1]);
    wbuf[e] = (u32)lo | ((u32)hi << 16);
  }
  u32* dst = (u32*)&xnT[((size_t)(b*NPIX + p0 + pl)) * CCH + c0 + cq];
  #pragma unroll
  for (int e = 0; e < 8; ++e) dst[e] = wbuf[e];
}

// ---------------- merged QKV GEMM (bf16 compute) -> fp8 Q/K/V outputs ----------------
__global__ __launch_bounds__(256, 2) void gemm_qkv(const u16* __restrict__ xnT,
                                                   const u16* __restrict__ wq_bf,
                                                   u8* __restrict__ outQ,
                                                   u8* __restrict__ outK,
                                                   u8* __restrict__ outV) {
  __shared__ __align__(16) char smem[65536];

  const int id = blockIdx.x;
  const int wg = (id & 7) * 192 + (id >> 3);
  const bool mode0 = (wg < 1024);
  int rt, ct;
  if (mode0) { rt = wg >> 3; ct = wg & 7; }
  else       { int w1 = wg - 1024; rt = w1 & 3; ct = w1 >> 2; }

  const char* Ab = mode0 ? (const char*)xnT + (size_t)rt * 131072
                         : (const char*)wq_bf + (size_t)(8 + rt) * 131072;
  const char* Bb = mode0 ? (const char*)wq_bf + (size_t)ct * 131072
                         : (const char*)xnT + (size_t)ct * 131072;

  const int t = threadIdx.x;
  const int lane = t & 63, w = t >> 6;
  const int q = lane & 31, hi = lane >> 5;
  const int rh = (w >> 1) * 64, ch = (w & 1) * 64;

  int soff[4];
  #pragma unroll
  for (int i = 0; i < 4; ++i) {
    int p = w*4096 + i*1024 + lane*16;
    int lrow = p >> 9, off = p & 511;
    int loff = off ^ ((lrow & 15) << 4);
    soff[i] = (lrow*4 + (loff >> 7)) * 1024 + (loff & 127);
  }

  #pragma unroll
  for (int i = 0; i < 4; ++i) {
    gload16(Ab + soff[i], smem +         w*4096 + i*1024);
    gload16(Bb + soff[i], smem + 16384 + w*4096 + i*1024);
  }

  f32x16 acc[2][2] = {};

  for (int kt = 0; kt < 8; ++kt) {
    asm volatile("s_waitcnt vmcnt(0)" ::: "memory");
    __syncthreads();
    const char* cur = smem + (kt & 1) * 32768;
    if (kt + 1 < 8) {
      char* nxt = smem + ((kt + 1) & 1) * 32768;
      #pragma unroll
      for (int i = 0; i < 4; ++i) {
        gload16(Ab + (kt+1)*128 + soff[i], nxt +         w*4096 + i*1024);
        gload16(Bb + (kt+1)*128 + soff[i], nxt + 16384 + w*4096 + i*1024);
      }
    }
    __builtin_amdgcn_s_setprio(1);
    #pragma unroll
    for (int ck = 0; ck < 4; ++ck) {
      short8 af0 = rd512(cur,         rh + q,      ck, hi);
      short8 af1 = rd512(cur,         rh + 32 + q, ck, hi);
      short8 bf0 = rd512(cur + 16384, ch + q,      ck, hi);
      short8 bf1 = rd512(cur + 16384, ch + 32 + q, ck, hi);
      acc[0][0] = __builtin_amdgcn_mfma_f32_32x32x16_bf16(af0, bf0, acc[0][0], 0, 0, 0);
      acc[0][1] = __builtin_amdgcn_mfma_f32_32x32x16_bf16(af0, bf1, acc[0][1], 0, 0, 0);
      acc[1][0] = __builtin_amdgcn_mfma_f32_32x32x16_bf16(af1, bf0, acc[1][0], 0, 0, 0);
      acc[1][1] = __builtin_amdgcn_mfma_f32_32x32x16_bf16(af1, bf1, acc[1][1], 0, 0, 0);
    }
    __builtin_amdgcn_s_setprio(0);
  }

  // epilogue: fp8 transpose via LDS, then 64B/thread coalesced stores
  __syncthreads();
  u8* Dt = (u8*)smem;   // [128][144] fp8
  #pragma unroll
  for (int r = 0; r < 16; ++r) {
    int ar = (r & 3) + 8*(r >> 2) + 4*hi;
    Dt[(rh +      ar) * 144 + ch +      q] = f2fp8(acc[0][0][r]);
    Dt[(rh +      ar) * 144 + ch + 32 + q] = f2fp8(acc[0][1][r]);
    Dt[(rh + 32 + ar) * 144 + ch +      q] = f2fp8(acc[1][0][r]);
    Dt[(rh + 32 + ar) * 144 + ch + 32 + q] = f2fp8(acc[1][1][r]);
  }
  __syncthreads();

  const int rl = t >> 1, hoff = (t & 1) * 64;
  uint4 buf[4];
  const uint4* s4 = reinterpret_cast<const uint4*>(&Dt[rl*144 + hoff]);
  #pragma unroll
  for (int e = 0; e < 4; ++e) buf[e] = s4[e];

  u8* gdst;
  if (mode0) {
    const int tok0 = rt * 128;
    const int b = tok0 >> 10, pix0 = tok0 & 1023;
    const int h = ct & 3;
    u8* base = (ct >= 4) ? outK : outQ;
    gdst = base + ((size_t)((b*NHEAD + h)) * NPIX + pix0 + rl) * HDIM + hoff;
  } else {
    const int m0 = rt * 128, tok0 = ct * 128;
    const int b = tok0 >> 10, pix0 = tok0 & 1023;
    gdst = outV + ((size_t)(b*CCH + m0 + rl)) * NPIX + pix0 + hoff;
  }
  uint4* g4 = reinterpret_cast<uint4*>(gdst);
  #pragma unroll
  for (int e = 0; e < 4; ++e) g4[e] = buf[e];
}

// ---------------- proj GEMM: dbuf-pipelined, fused residual + bias -> fp32 out ----------------
__global__ __launch_bounds__(256, 2) void gemm_proj(const u16* __restrict__ wp_bf,
                                                    const u16* __restrict__ attnO,
                                                    const float* __restrict__ xres,
                                                    const float* __restrict__ bias,
                                                    float* __restrict__ outF) {
  __shared__ __align__(16) char smem[65536];

  const int id = blockIdx.x;
  const int wg = (id & 7) * 64 + (id >> 3);
  const int rt = wg & 3, ct = wg >> 2;

  const char* Ab = (const char*)wp_bf + (size_t)rt * 131072;
  const char* Bb = (const char*)attnO + (size_t)ct * 131072;

  const int t = threadIdx.x;
  const int lane = t & 63, w = t >> 6;
  const int q = lane & 31, hi = lane >> 5;
  const int rh = (w >> 1) * 64, ch = (w & 1) * 64;

  int soff[4];
  #pragma unroll
  for (int i = 0; i < 4; ++i) {
    int p = w*4096 + i*1024 + lane*16;
    int lrow = p >> 9, off = p & 511;
    int loff = off ^ ((lrow & 15) << 4);
    soff[i] = (lrow*4 + (loff >> 7)) * 1024 + (loff & 127);
  }

  #pragma unroll
  for (int i = 0; i < 4; ++i) {
    gload16(Ab + soff[i], smem +         w*4096 + i*1024);
    gload16(Bb + soff[i], smem + 16384 + w*4096 + i*1024);
  }

  f32x16 acc[2][2] = {};

  for (int kt = 0; kt < 8; ++kt) {
    asm volatile("s_waitcnt vmcnt(0)" ::: "memory");
    __syncthreads();
    const char* cur = smem + (kt & 1) * 32768;
    if (kt + 1 < 8) {
      char* nxt = smem + ((kt + 1) & 1) * 32768;
      #pragma unroll
      for (int i = 0; i < 4; ++i) {
        gload16(Ab + (kt+1)*128 + soff[i], nxt +         w*4096 + i*1024);
        gload16(Bb + (kt+1)*128 + soff[i], nxt + 16384 + w*4096 + i*1024);
      }
    }
    __builtin_amdgcn_s_setprio(1);
    #pragma unroll
    for (int ck = 0; ck < 4; ++ck) {
      short8 af0 = rd512(cur,         rh + q,      ck, hi);
      short8 af1 = rd512(cur,         rh + 32 + q, ck, hi);
      short8 bf0 = rd512(cur + 16384, ch + q,      ck, hi);
      short8 bf1 = rd512(cur + 16384, ch + 32 + q, ck, hi);
      acc[0][0] = __builtin_amdgcn_mfma_f32_32x32x16_bf16(af0, bf0, acc[0][0], 0, 0, 0);
      acc[0][1] = __builtin_amdgcn_mfma_f32_32x32x16_bf16(af0, bf1, acc[0][1], 0, 0, 0);
      acc[1][0] = __builtin_amdgcn_mfma_f32_32x32x16_bf16(af1, bf0, acc[1][0], 0, 0, 0);
      acc[1][1] = __builtin_amdgcn_mfma_f32_32x32x16_bf16(af1, bf1, acc[1][1], 0, 0, 0);
    }
    __builtin_amdgcn_s_setprio(0);
  }

  const int m0 = rt * 128, tok0 = ct * 128;
  const int b = tok0 >> 10, pix0 = tok0 & 1023;
  #pragma unroll
  for (int r = 0; r < 16; ++r) {
    int ar = (r & 3) + 8*(r >> 2) + 4*hi;
    int m0r = m0 + rh + ar, m1r = m0 + rh + 32 + ar;
    size_t o00 = ((size_t)(b*CCH + m0r)) * NPIX + pix0 + ch + q;
    size_t o01 = o00 + 32;
    size_t o10 = ((size_t)(b*CCH + m1r)) * NPIX + pix0 + ch + q;
    size_t o11 = o10 + 32;
    outF[o00] = xres[o00] + acc[0][0][r] + bias[m0r];
    outF[o01] = xres[o01] + acc[0][1][r] + bias[m0r];
    outF[o10] = xres[o10] + acc[1][0][r] + bias[m1r];
    outF[o11] = xres[o11] + acc[1][1][r] + bias[m1r];
  }
}

// ---------------- Flash attention: fp8, KVBLK=128 (8 tiles), counted-vmcnt pipeline ----------------
// Qt,Kt token-major fp8 [bh][pix][128]; Vb channel-major fp8 [b*512+m][1024].
// K LDS: [128 kv][128B], swz byte^=((kv&15)<<3).  V LDS: [128 c][128B], swz byte^=((c&15)<<3).
// Note (cg*32+q)&15 == q&15, so one swizzle constant serves QK and PV reads.
__global__ __launch_bounds__(256, 2) void attn_k(const u8* __restrict__ Qt,
                                                 const u8* __restrict__ Kt,
                                                 const u8* __restrict__ Vb,
                                                 u16* __restrict__ attnO) {
  int id = blockIdx.x;
  int swz = (id & 7) * 64 + (id >> 3);
  const int qt = swz & 7;
  const int h  = (swz >> 3) & 3;
  const int b  = swz >> 5;
  const int bh = b * NHEAD + h;

  __shared__ __align__(16) char smem[65536];  // K dbuf 2x16K @0 | V dbuf 2x16K @32768

  const int t = threadIdx.x;
  const int lane = t & 63, w = t >> 6;
  const int q = lane & 31, hi = lane >> 5;

  const u8*   Qb    = Qt + ((size_t)bh * NPIX + qt*128 + w*32 + q) * HDIM;
  const char* Kbase = (const char*)Kt + (size_t)bh * NPIX * HDIM;
  const char* Vbase = (const char*)Vb + ((size_t)b*CCH + h*HDIM) * NPIX;

  i64 qf[8];
  #pragma unroll
  for (int ck = 0; ck < 8; ++ck)
    qf[ck] = *reinterpret_cast<const i64*>(Qb + ck*16 + hi*8);

  // staging source offsets (pre-swizzled, linear LDS dest), 4x16B per thread per tensor
  int koff[4], voff[4];
  #pragma unroll
  for (int i = 0; i < 4; ++i) {
    int d = i*4096 + w*1024 + lane*16;   // 0..16383
    int r = d >> 7, x = d & 127;
    koff[i] = r*128 + (x ^ ((r & 15) << 3));
    voff[i] = r*1024 + (x ^ ((r & 15) << 3));   // V: row r = channel r, global stride 1024
  }

  const int ksw = (q & 15) << 3;

  f32x16 of[4] = {};
  float l_run = 0.f;
  i64 pf[8];
  const float qs2 = 0.08838834764831845f * 1.44269504088896f;

  // prologue: K0->kb0, K1->kb1, V0->vb0 (K before V); full drain once
  #pragma unroll
  for (int i = 0; i < 4; ++i)
    gload16(Kbase + koff[i],         smem +         i*4096 + w*1024);
  #pragma unroll
  for (int i = 0; i < 4; ++i)
    gload16(Kbase + 16384 + koff[i], smem + 16384 + i*4096 + w*1024);
  #pragma unroll
  for (int i = 0; i < 4; ++i)
    gload16(Vbase + voff[i],         smem + 32768 + i*4096 + w*1024);
  asm volatile("s_waitcnt vmcnt(0)" ::: "memory");
  __syncthreads();

  // QK(0) + softmax(0)
  {
    f32x16 sn0 = {}, sn1 = {}, sn2 = {}, sn3 = {};
    #pragma unroll
    for (int ck = 0; ck < 8; ++ck) {
      const int co = (ck*16 + hi*8) ^ ksw;
      const i64 kf0 = *reinterpret_cast<const i64*>(smem + (q)*128      + co);
      const i64 kf1 = *reinterpret_cast<const i64*>(smem + (32+q)*128   + co);
      const i64 kf2 = *reinterpret_cast<const i64*>(smem + (64+q)*128   + co);
      const i64 kf3 = *reinterpret_cast<const i64*>(smem + (96+q)*128   + co);
      sn0 = __builtin_amdgcn_mfma_f32_32x32x16_fp8_fp8(kf0, qf[ck], sn0, 0, 0, 0);
      sn1 = __builtin_amdgcn_mfma_f32_32x32x16_fp8_fp8(kf1, qf[ck], sn1, 0, 0, 0);
      sn2 = __builtin_amdgcn_mfma_f32_32x32x16_fp8_fp8(kf2, qf[ck], sn2, 0, 0, 0);
      sn3 = __builtin_amdgcn_mfma_f32_32x32x16_fp8_fp8(kf3, qf[ck], sn3, 0, 0, 0);
    }
    float ps = 0.f;
    #pragma unroll
    for (int g = 0; g < 4; ++g) {
      const f32x16& sn = (g == 0) ? sn0 : (g == 1) ? sn1 : (g == 2) ? sn2 : sn3;
      float p[16];
      float psa = 0.f, psb = 0.f;
      #pragma unroll
      for (int r = 0; r < 8; ++r)  { p[r] = exp2f(sn[r] * qs2); psa += p[r]; }
      #pragma unroll
      for (int r = 8; r < 16; ++r) { p[r] = exp2f(sn[r] * qs2); psb += p[r]; }
      u32 w0 = pack4_fp8(p[0], p[1], p[2], p[3]);
      u32 w1 = pack4_fp8(p[4], p[5], p[6], p[7]);
      u32 w2 = pack4_fp8(p[8], p[9], p[10], p[11]);
      u32 w3 = pack4_fp8(p[12], p[13], p[14], p[15]);
      PLSWAP(w0, w1);
      PLSWAP(w2, w3);
      pf[g*2]   = (i64)(((unsigned long long)w1 << 32) | w0);
      pf[g*2+1] = (i64)(((unsigned long long)w3 << 32) | w2);
      ps += psa + psb;
    }
    ps += __shfl_xor(ps, 32);
    l_run += ps;
  }

  // main loop: 8 tiles of 128 kv; iter tt = {QK_{tt+1} || PV_tt}, counted waits, raw barriers
  for (int tt = 0; tt < 8; ++tt) {
    asm volatile("s_waitcnt vmcnt(4)" ::: "memory");   // K(tt+1) landed; V(tt) may fly
    __builtin_amdgcn_s_barrier();

    const char* kcur = smem + (((tt+1) & 1) << 14);
    const char* vcur = smem + 32768 + ((tt & 1) << 14);

    // issue K first (older), then V
    if (tt + 2 < 8) {
      char* kd = smem + ((tt & 1) << 14);
      #pragma unroll
      for (int i = 0; i < 4; ++i)
        gload16(Kbase + (size_t)(tt+2)*16384 + koff[i], kd + i*4096 + w*1024);
    }
    if (tt + 1 < 8) {
      char* vd = smem + 32768 + (((tt+1) & 1) << 14);
      #pragma unroll
      for (int i = 0; i < 4; ++i)
        gload16(Vbase + (size_t)(tt+1)*128 + voff[i], vd + i*4096 + w*1024);
    }

    f32x16 sn0 = {}, sn1 = {}, sn2 = {}, sn3 = {};
    __builtin_amdgcn_s_setprio(1);
    if (tt + 1 < 8) {
      #pragma unroll
      for (int ck = 0; ck < 8; ++ck) {
        const int co = (ck*16 + hi*8) ^ ksw;
        const i64 kf0 = *reinterpret_cast<const i64*>(kcur + (q)*128    + co);
        const i64 kf1 = *reinterpret_cast<const i64*>(kcur + (32+q)*128 + co);
        const i64 kf2 = *reinterpret_cast<const i64*>(kcur + (64+q)*128 + co);
        const i64 kf3 = *reinterpret_cast<const i64*>(kcur + (96+q)*128 + co);
        sn0 = __builtin_amdgcn_mfma_f32_32x32x16_fp8_fp8(kf0, qf[ck], sn0, 0, 0, 0);
        sn1 = __builtin_amdgcn_mfma_f32_32x32x16_fp8_fp8(kf1, qf[ck], sn1, 0, 0, 0);
        sn2 = __builtin_amdgcn_mfma_f32_32x32x16_fp8_fp8(kf2, qf[ck], sn2, 0, 0, 0);
        sn3 = __builtin_amdgcn_mfma_f32_32x32x16_fp8_fp8(kf3, qf[ck], sn3, 0, 0, 0);
      }
    }
    __builtin_amdgcn_s_setprio(0);

    // V(tt) wait: leave this iter's fresh loads in flight
    if (tt < 6)       asm volatile("s_waitcnt vmcnt(8)" ::: "memory");
    else if (tt == 6) asm volatile("s_waitcnt vmcnt(4)" ::: "memory");
    else              asm volatile("s_waitcnt vmcnt(0)" ::: "memory");
    __builtin_amdgcn_s_barrier();

    // PV(tt): A = V(c x kv) fp8, B = P fp8; 4 cg x 8 kc
    __builtin_amdgcn_s_setprio(1);
    #pragma unroll
    for (int cg = 0; cg < 4; ++cg) {
      const char* vrow = vcur + (cg*32 + q)*128;
      #pragma unroll
      for (int kc = 0; kc < 8; ++kc) {
        const i64 vf = *reinterpret_cast<const i64*>(vrow + ((kc*16 + hi*8) ^ ksw));
        of[cg] = __builtin_amdgcn_mfma_f32_32x32x16_fp8_fp8(vf, pf[kc], of[cg], 0, 0, 0);
      }
    }
    __builtin_amdgcn_s_setprio(0);

    // softmax(tt+1)
    if (tt + 1 < 8) {
      float ps = 0.f;
      #pragma unroll
      for (int g = 0; g < 4; ++g) {
        const f32x16& sn = (g == 0) ? sn0 : (g == 1) ? sn1 : (g == 2) ? sn2 : sn3;
        float p[16];
        float psa = 0.f, psb = 0.f;
        #pragma unroll
        for (int r = 0; r < 8; ++r)  { p[r] = exp2f(sn[r] * qs2); psa += p[r]; }
        #pragma unroll
        for (int r = 8; r < 16; ++r) { p[r] = exp2f(sn[r] * qs2); psb += p[r]; }
        u32 w0 = pack4_fp8(p[0], p[1], p[2], p[3]);
        u32 w1 = pack4_fp8(p[4], p[5], p[6], p[7]);
        u32 w2 = pack4_fp8(p[8], p[9], p[10], p[11]);
        u32 w3 = pack4_fp8(p[12], p[13], p[14], p[15]);
        PLSWAP(w0, w1);
        PLSWAP(w2, w3);
        pf[g*2]   = (i64)(((unsigned long long)w1 << 32) | w0);
        pf[g*2+1] = (i64)(((unsigned long long)w3 << 32) | w2);
        ps += psa + psb;
      }
      ps += __shfl_xor(ps, 32);
      l_run += ps;
    }
  }

  // epilogue: D[c][q] layout, c = cg*32 + (r&3)+8*(r>>2)+4*hi
  float inv = 1.f / l_run;
  u16* orow = attnO + ((size_t)(b*NPIX + qt*128 + w*32 + q)) * CCH + h*HDIM;
  #pragma unroll
  for (int cg = 0; cg < 4; ++cg) {
    #pragma unroll
    for (int u = 0; u < 8; ++u) {
      int c = cg*32 + ((2*u) & 3) + 8*(u >> 1) + 4*hi;
      u32 pk = (u32)f2bf(of[cg][2*u] * inv) | ((u32)f2bf(of[cg][2*u+1] * inv) << 16);
      *reinterpret_cast<u32*>(&orow[c]) = pk;
    }
  }
}

// ---------------- launch ----------------
extern "C" void kernel_launch(void* const* d_in, const int* in_sizes, int n_in,
                              void* d_out, int out_size, void* d_ws, size_t ws_size,
                              hipStream_t stream) {
  const float* x     = (const float*)d_in[0];
  const float* gamma = (const float*)d_in[1];
  const float* beta  = (const float*)d_in[2];
  const float* wqkv  = (const float*)d_in[3];
  const float* wproj = (const float*)d_in[4];
  const float* bproj = (const float*)d_in[5];
  float* out = (float*)d_out;

  char* ws = (char*)d_ws;
  float* part   = (float*)ws;                          // 8 KB
  u16*   xnT    = (u16*)(ws + 8192);                   // 16 MB [16384][512] bf16
  u16*   wq_bf  = (u16*)(ws + 8192 + (16u<<20));       // 1.5 MB
  u16*   wp_bf  = (u16*)((char*)wq_bf + 1572864);      // 0.5 MB
  u8*    Qt     = (u8*)((char*)wp_bf + 524288);        // 8 MB fp8 [bh][1024][128]
  u8*    Kt     = (u8*)((char*)Qt + (8u<<20));         // 8 MB fp8
  u8*    Vb     = (u8*)((char*)Kt + (8u<<20));         // 8 MB fp8 [b*512+m][1024]
  u16*   attnO  = (u16*)((char*)Vb + (8u<<20));        // 16 MB bf16 [16384][512]

  gn_stats_wconv<<<dim3(2048), dim3(256), 0, stream>>>(x, part, wqkv, wproj, wq_bf, wp_bf);
  gn_apply_t<<<dim3(16, 8, BATCH), dim3(256), 0, stream>>>(x, gamma, beta, part, xnT);

  gemm_qkv<<<dim3(1536), dim3(256), 0, stream>>>(xnT, wq_bf, Qt, Kt, Vb);

  attn_k<<<dim3(512), dim3(256), 0, stream>>>(Qt, Kt, Vb, attnO);

  gemm_proj<<<dim3(512), dim3(256), 0, stream>>>(wp_bf, attnO, x, bproj, out);
}